// Round 10
// baseline (601.847 us; speedup 1.0000x reference)
//
#include <hip/hip_runtime.h>
#include <cstdint>
#include <cstddef>

// ---------- types ----------
typedef __attribute__((ext_vector_type(8))) __bf16 bf16x8;
typedef __attribute__((ext_vector_type(4))) float f32x4;
typedef __attribute__((ext_vector_type(8))) unsigned short us8;
typedef __attribute__((ext_vector_type(4))) unsigned short us4;

__device__ inline unsigned short f2bf(float f) {
    unsigned int u = __float_as_uint(f);
    u += 0x7fffu + ((u >> 16) & 1u);   // RNE
    return (unsigned short)(u >> 16);
}

// pack two f32 -> two bf16 by truncation (1 instr); |rel err| < 2^-8, fine for P
__device__ inline unsigned int pkbf_t(float hi, float lo) {
    return __builtin_amdgcn_perm(__float_as_uint(hi), __float_as_uint(lo), 0x07060302u);
}

// raw 2^x: skip the OCML denormal-guard libcall (inputs bounded; subnormal
// results contribute 0 to softmax anyway). 1 instr vs ~6.
__device__ inline float exp2_raw(float x) {
    float r;
    asm("v_exp_f32 %0, %1" : "=v"(r) : "v"(x));
    return r;
}

__device__ inline void async_copy16(const void* g, void* l) {
    __builtin_amdgcn_global_load_lds(
        (const __attribute__((address_space(1))) unsigned int*)g,
        (__attribute__((address_space(3))) unsigned int*)l, 16, 0, 0);
}

// ---------- fp32 -> bf16 convert ----------
__global__ __launch_bounds__(256) void cvt_bf16(const float* __restrict__ in,
                                                unsigned short* __restrict__ out, int n4) {
    int i = blockIdx.x * 256 + threadIdx.x;
    if (i < n4) {
        float4 v = ((const float4*)in)[i];
        us4 o;
        o[0] = f2bf(v.x); o[1] = f2bf(v.y); o[2] = f2bf(v.z); o[3] = f2bf(v.w);
        ((us4*)out)[i] = o;
    }
}

// ---------- layernorm (fp32 in, bf16 out) ----------
__global__ __launch_bounds__(256) void ln_bf16(const float* __restrict__ X,
                                               const float* __restrict__ g,
                                               const float* __restrict__ b,
                                               unsigned short* __restrict__ out) {
    int row = blockIdx.x;
    int t = threadIdx.x;
    float4 v = ((const float4*)(X + (size_t)row * 1024))[t];
    float s  = v.x + v.y + v.z + v.w;
    float s2 = v.x * v.x + v.y * v.y + v.z * v.z + v.w * v.w;
#pragma unroll
    for (int m = 1; m < 64; m <<= 1) {
        s  += __shfl_xor(s, m, 64);
        s2 += __shfl_xor(s2, m, 64);
    }
    __shared__ float red[8];
    int w = t >> 6, l = t & 63;
    if (l == 0) { red[w] = s; red[4 + w] = s2; }
    __syncthreads();
    s  = red[0] + red[1] + red[2] + red[3];
    s2 = red[4] + red[5] + red[6] + red[7];
    float mu  = s * (1.0f / 1024.0f);
    float var = s2 * (1.0f / 1024.0f) - mu * mu;
    float rs  = rsqrtf(var + 1e-5f);
    int c = t * 4;
    float4 gv = *(const float4*)(g + c);
    float4 bv = *(const float4*)(b + c);
    us4 o;
    o[0] = f2bf((v.x - mu) * rs * gv.x + bv.x);
    o[1] = f2bf((v.y - mu) * rs * gv.y + bv.y);
    o[2] = f2bf((v.z - mu) * rs * gv.z + bv.z);
    o[3] = f2bf((v.w - mu) * rs * gv.w + bv.w);
    *(us4*)(out + (size_t)row * 1024 + c) = o;
}

// ---------- NT GEMM: BMt x 128 tile, BK=32, dist-2 pipeline + T2 swizzle ----------
// template<EPI, BMt>: BMt=128 -> wave-tile 64x64 (round-9 verified config);
// BMt=256 -> wave-tile 128x64: 12 ds_read_b128 per 32 MFMA (-25% LDS issue
// per FLOP; LDS BW demand drops below the 85 B/cy ceiling) and -25% staging
// VALU per FLOP. 4 waves, 2x2 wave grid, triple-buffered LDS
// (48 / 72 KB -> 3 / 2 blocks per CU).
// Pipeline (ledger CORRECTED from r5-r9): at iter kt, outstanding = stages
// kt,kt+1 (2*NCP copies); vmcnt(NCP) retires exactly stage kt; barrier
// publishes; STAGE(kt+2) into buf freed at kt-1. Never vmcnt(0) in steady state.
// T2 swizzle both-sides: rows are 64 B = 4 chunks; f(r) = (r>>1)&3;
// global source chunk pre-XORed, linear LDS dest, read chunk quad^f.
// EPI: 1 gelu(bias)->bf16 ; 2 bias+resid->fp32 ; 6 fused QKV epilogue.
#define BK 32

template <int EPI, int BMt>
__global__ __launch_bounds__(256, 2) void gemm_nt(const unsigned short* __restrict__ A,
                                                  const unsigned short* __restrict__ B,
                                                  const float* __restrict__ bias,
                                                  const float* __restrict__ resid,
                                                  void* __restrict__ Cout, int N, int K) {
    constexpr int WTM = BMt / 2;          // per-wave M tile (64 / 128)
    constexpr int MF  = WTM / 16;         // m-frags per wave (4 / 8)
    constexpr int NA  = BMt / 64;         // A copies per thread (2 / 4)
    constexpr int NCP = NA + 2;           // copies per stage per thread (4 / 6)

    __shared__ __align__(16) unsigned short As[3][BMt * BK];
    __shared__ __align__(16) unsigned short Bs[3][128 * BK];
    const int tid = threadIdx.x;
    const int lane = tid & 63, w = tid >> 6;
    const int quad = lane >> 4, l16 = lane & 15;
    const int wr = w >> 1, wc = w & 1;
    const int swq = quad ^ ((l16 >> 1) & 3);   // swizzled read chunk

    const int gx = gridDim.x;
    const int nwg = gx * gridDim.y;
    int wg = blockIdx.y * gx + blockIdx.x;
    if (!(nwg & 7)) wg = (wg & 7) * (nwg >> 3) + (wg >> 3);
    const size_t bm = (size_t)(wg / gx) * BMt;
    const size_t bn = (size_t)(wg % gx) * 128;

    // hoisted per-thread staging sources (pre-swizzled chunk within row)
    const unsigned short* pA[NA];
    const unsigned short* pB[2];
#pragma unroll
    for (int j = 0; j < NA; j++) {
        int c = j * 256 + tid;            // chunk id (16 B units)
        int r = c >> 2, ch = c & 3;
        pA[j] = A + (bm + r) * (size_t)K + ((ch ^ ((r >> 1) & 3)) << 3);
    }
#pragma unroll
    for (int j = 0; j < 2; j++) {
        int c = j * 256 + tid;
        int r = c >> 2, ch = c & 3;
        pB[j] = B + (bn + r) * (size_t)K + ((ch ^ ((r >> 1) & 3)) << 3);
    }

#define STAGE(buf, kt)                                                        \
    {                                                                         \
        const int koff = (kt)*BK;                                             \
        _Pragma("unroll") for (int j = 0; j < NA; j++)                        \
            async_copy16(pA[j] + koff, &As[buf][(j * 256 + tid) * 8]);        \
        _Pragma("unroll") for (int j = 0; j < 2; j++)                         \
            async_copy16(pB[j] + koff, &Bs[buf][(j * 256 + tid) * 8]);        \
    }

    f32x4 acc[MF][4];
#pragma unroll
    for (int i = 0; i < MF; i++)
#pragma unroll
        for (int j = 0; j < 4; j++) acc[i][j] = (f32x4){0.f, 0.f, 0.f, 0.f};

    const int nk = K / BK;

    STAGE(0, 0);
    STAGE(1, 1);

    for (int kt = 0; kt < nk; ++kt) {
        const int cur = kt % 3;
        // retire exactly stage kt (issued 2 iterations ago); leave kt+1 (and
        // kt+2 once staged) in flight
        if (kt + 1 < nk) {
            if constexpr (NCP == 4) {
                asm volatile("s_waitcnt vmcnt(4)" ::: "memory");
            } else {
                asm volatile("s_waitcnt vmcnt(6)" ::: "memory");
            }
        } else {
            asm volatile("s_waitcnt vmcnt(0)" ::: "memory");
        }
        asm volatile("s_barrier" ::: "memory");

        if (kt + 2 < nk) {
            STAGE((kt + 2) % 3, kt + 2);
        }

        bf16x8 bfr[4];
#pragma unroll
        for (int nt = 0; nt < 4; nt++)
            bfr[nt] = *(const bf16x8*)&Bs[cur][(wc * 64 + nt * 16 + l16) * BK + swq * 8];
        bf16x8 af[MF];
#pragma unroll
        for (int i = 0; i < MF; i++)
            af[i] = *(const bf16x8*)&As[cur][(wr * WTM + i * 16 + l16) * BK + swq * 8];

        __builtin_amdgcn_s_setprio(1);
#pragma unroll
        for (int i = 0; i < MF; i++)
#pragma unroll
            for (int nt = 0; nt < 4; nt++)
                acc[i][nt] = __builtin_amdgcn_mfma_f32_16x16x32_bf16(af[i], bfr[nt],
                                                                     acc[i][nt], 0, 0, 0);
        __builtin_amdgcn_s_setprio(0);
        __builtin_amdgcn_sched_barrier(0);
    }
#undef STAGE

#pragma unroll
    for (int mf = 0; mf < MF; mf++) {
#pragma unroll
        for (int nt = 0; nt < 4; nt++) {
#pragma unroll
            for (int r = 0; r < 4; r++) {
                size_t row = bm + wr * WTM + mf * 16 + quad * 4 + r;
                size_t col = bn + wc * 64 + nt * 16 + l16;
                float v = acc[mf][nt][r] + bias[col];
                if (EPI == 1) {
                    v = 0.5f * v * (1.0f + erff(v * 0.70710678118654752f));
                    ((unsigned short*)Cout)[row * N + col] = f2bf(v);
                } else if (EPI == 2) {
                    ((float*)Cout)[row * N + col] = v + resid[row * N + col];
                } else if (EPI == 6) {
                    int sel = (int)(bn >> 10);
                    if (sel == 0) {
                        ((unsigned short*)Cout)[row * 1024 + col] =
                            f2bf(v * 0.18033688011112042f);  // 0.125*log2(e)
                    } else {
                        int key = (int)row & 2047;
                        int bh  = (((int)row >> 11) << 4) | (((int)col >> 6) & 15);
                        int dh  = (int)col & 63;
                        size_t addr;
                        if (sel == 1)
                            addr = 8388608 + (size_t)bh * 131072 +
                                   (size_t)(key >> 6) * 4096 + (size_t)(key & 63) * 64 +
                                   ((((dh >> 3) ^ (key & 7))) << 3) + (dh & 7);
                        else
                            addr = 16777216 + (size_t)bh * 131072 +
                                   (size_t)(key >> 6) * 4096 + (size_t)dh * 64 +
                                   (((((key >> 3) & 7) ^ (dh & 7))) << 3) + (key & 7);
                        ((unsigned short*)Cout)[addr] = f2bf(v);
                    }
                }
            }
        }
    }
}

// ---------- flash attention v6: raw v_exp + l-via-MFMA ----------
// grid 1024: bh = bid & 63 (qblocks of a bh stay on one XCD -> K/V L2-local),
// qblk = bid >> 6. Pipeline = verified v4: dbuf K, late-prefetch V, counted
// vmcnt 4->2->0, raw s_barrier.
// VALU cuts: (1) inline-asm v_exp_f32 (no OCML guard); (2) denominator l
// computed by an extra MFMA with ones-A (D[row][q] = sum_k P[k][q], identical
// across rows/quads) -> removes 24 adds/tile + the cross-quad shfl reduce.
__global__ __launch_bounds__(256) void attn_kernel(const unsigned short* __restrict__ Q,
                                                   const unsigned short* __restrict__ Kb,
                                                   const unsigned short* __restrict__ Vtb,
                                                   unsigned short* __restrict__ O) {
    const int bh   = blockIdx.x & 63;
    const int qblk = blockIdx.x >> 6;
    const int b = bh >> 4, h = bh & 15;
    const int tid = threadIdx.x, lane = tid & 63, w = tid >> 6;
    const int quad = lane >> 4, l16 = lane & 15;
    const int sw = l16 & 7;

    __shared__ __align__(16) unsigned short smem[20480];   // 40 KB
    unsigned short* Vts = smem + 8192;                     // [64 dh][swz 64 key]
    unsigned short* Psw = smem + 12288 + w * 2048;         // per-wave [32 q][swz 64 key]

    const size_t qrow0 = (size_t)b * 2048 + (size_t)qblk * 128 + w * 32;
    const int hcol = h * 64;

    // Q fragment loads first: oldest vmem ops, drained by the first vmcnt(4)
    bf16x8 qfr[2][2];
#pragma unroll
    for (int qf = 0; qf < 2; qf++)
#pragma unroll
        for (int kp = 0; kp < 2; kp++)
            qfr[qf][kp] = *(const bf16x8*)(Q + (qrow0 + qf * 16 + l16) * 1024 +
                                           hcol + kp * 32 + quad * 8);

    const unsigned short* ksrc = Kb  + (size_t)bh * 131072;
    const unsigned short* vsrc = Vtb + (size_t)bh * 131072;

    // prologue: stage K(0) -> buf0, V(0) -> Vts
    async_copy16(ksrc + tid * 8,        smem + tid * 8);
    async_copy16(ksrc + 2048 + tid * 8, smem + 2048 + tid * 8);
    async_copy16(vsrc + tid * 8,        Vts + tid * 8);
    async_copy16(vsrc + 2048 + tid * 8, Vts + 2048 + tid * 8);

    // ones A-fragment for the denominator MFMA
    us8 one_us;
#pragma unroll
    for (int j = 0; j < 8; j++) one_us[j] = 0x3F80;        // bf16 1.0
    const bf16x8 ones = *(const bf16x8*)&one_us;

    f32x4 acc[4][2];
#pragma unroll
    for (int df = 0; df < 4; df++)
#pragma unroll
        for (int qf = 0; qf < 2; qf++) acc[df][qf] = (f32x4){0.f, 0.f, 0.f, 0.f};
    f32x4 acc_l[2] = {(f32x4){0.f, 0.f, 0.f, 0.f}, (f32x4){0.f, 0.f, 0.f, 0.f}};

    for (int kt = 0; kt < 32; ++kt) {
        unsigned short* Ks = (kt & 1) ? (smem + 4096) : smem;   // current K buffer
        if (kt < 31) {
            unsigned short* Kd = (kt & 1) ? smem : (smem + 4096);
            const unsigned short* kg = ksrc + (size_t)(kt + 1) * 4096;
            async_copy16(kg + tid * 8,        Kd + tid * 8);
            async_copy16(kg + 2048 + tid * 8, Kd + 2048 + tid * 8);
            asm volatile("s_waitcnt vmcnt(4)" ::: "memory");    // K(kt) landed
        } else {
            asm volatile("s_waitcnt vmcnt(2)" ::: "memory");    // K(31) landed
        }
        asm volatile("s_barrier" ::: "memory");

        // S^T[64 key][32 q] = K Q^T
        f32x4 s[4][2];
#pragma unroll
        for (int mf = 0; mf < 4; mf++)
#pragma unroll
            for (int qf = 0; qf < 2; qf++) s[mf][qf] = (f32x4){0.f, 0.f, 0.f, 0.f};
        __builtin_amdgcn_s_setprio(1);
#pragma unroll
        for (int kp = 0; kp < 2; kp++) {
#pragma unroll
            for (int mf = 0; mf < 4; mf++) {
                bf16x8 kf = *(const bf16x8*)&Ks[(mf * 16 + l16) * 64 +
                                                (((kp * 4 + quad) ^ sw) << 3)];
#pragma unroll
                for (int qf = 0; qf < 2; qf++)
                    s[mf][qf] = __builtin_amdgcn_mfma_f32_16x16x32_bf16(kf, qfr[qf][kp],
                                                                        s[mf][qf], 0, 0, 0);
            }
        }
        __builtin_amdgcn_s_setprio(0);

        // p = exp2(s) (raw v_exp); trunc-pack into Psw (no VALU row-sum)
#pragma unroll
        for (int mf = 0; mf < 4; mf++)
#pragma unroll
            for (int qf = 0; qf < 2; qf++) {
                float e0 = exp2_raw(s[mf][qf][0]);
                float e1 = exp2_raw(s[mf][qf][1]);
                float e2 = exp2_raw(s[mf][qf][2]);
                float e3 = exp2_raw(s[mf][qf][3]);
                *(uint2*)&Psw[(qf * 16 + l16) * 64 +
                              (((mf * 2 + (quad >> 1)) ^ sw) << 3) + ((quad & 1) << 2)] =
                    make_uint2(pkbf_t(e1, e0), pkbf_t(e3, e2));
            }
        asm volatile("s_waitcnt lgkmcnt(0)" ::: "memory");

        if (kt < 31) {
            asm volatile("s_waitcnt vmcnt(2)" ::: "memory");    // V(kt) landed
        } else {
            asm volatile("s_waitcnt vmcnt(0)" ::: "memory");
        }
        asm volatile("s_barrier" ::: "memory");

        // out^T[64 dh][32 q] += V^T P^T ; denominator row via ones-MFMA
        __builtin_amdgcn_s_setprio(1);
#pragma unroll
        for (int kp = 0; kp < 2; kp++) {
            bf16x8 pf[2];
#pragma unroll
            for (int qf = 0; qf < 2; qf++) {
                pf[qf] = *(const bf16x8*)&Psw[(qf * 16 + l16) * 64 +
                                              (((kp * 4 + quad) ^ sw) << 3)];
                acc_l[qf] = __builtin_amdgcn_mfma_f32_16x16x32_bf16(ones, pf[qf],
                                                                    acc_l[qf], 0, 0, 0);
            }
#pragma unroll
            for (int df = 0; df < 4; df++) {
                bf16x8 vf = *(const bf16x8*)&Vts[(df * 16 + l16) * 64 +
                                                 (((kp * 4 + quad) ^ sw) << 3)];
#pragma unroll
                for (int qf = 0; qf < 2; qf++)
                    acc[df][qf] = __builtin_amdgcn_mfma_f32_16x16x32_bf16(vf, pf[qf],
                                                                          acc[df][qf], 0, 0, 0);
            }
        }
        __builtin_amdgcn_s_setprio(0);

        asm volatile("s_barrier" ::: "memory");
        if (kt < 31) {
            const unsigned short* vg = vsrc + (size_t)(kt + 1) * 4096;
            async_copy16(vg + tid * 8,        Vts + tid * 8);
            async_copy16(vg + 2048 + tid * 8, Vts + 2048 + tid * 8);
        }
    }

    // epilogue: normalize, transpose through LDS, coalesced bf16 store.
    // acc_l rows are all identical (ones-A) -> inv uniform across quads.
    __syncthreads();
    float inv[2] = {1.f / acc_l[0][0], 1.f / acc_l[1][0]};
    unsigned short* Ls = smem;   // [64 dh][128 q] stride 130
#pragma unroll
    for (int df = 0; df < 4; df++)
#pragma unroll
        for (int qf = 0; qf < 2; qf++)
#pragma unroll
            for (int r = 0; r < 4; r++) {
                int dh = df * 16 + quad * 4 + r;
                int q  = w * 32 + qf * 16 + l16;
                Ls[dh * 130 + q] =
                    (unsigned short)((__float_as_uint(acc[df][qf][r] * inv[qf]) + 0x8000u) >> 16);
            }
    __syncthreads();
    int q = tid >> 1, dh0 = (tid & 1) * 32;
    size_t obase = ((size_t)b * 2048 + (size_t)qblk * 128 + q) * 1024 + hcol + dh0;
#pragma unroll
    for (int c = 0; c < 4; c++) {
        us8 o;
#pragma unroll
        for (int j = 0; j < 8; j++) o[j] = Ls[(dh0 + c * 8 + j) * 130 + q];
        *(us8*)(O + obase + c * 8) = o;
    }
}

// ---------- launch ----------
extern "C" void kernel_launch(void* const* d_in, const int* in_sizes, int n_in,
                              void* d_out, int out_size, void* d_ws, size_t ws_size,
                              hipStream_t stream) {
    const float* x     = (const float*)d_in[0];
    const float* ln1_g = (const float*)d_in[1];
    const float* ln1_b = (const float*)d_in[2];
    const float* ln2_g = (const float*)d_in[3];
    const float* ln2_b = (const float*)d_in[4];
    const float* wq = (const float*)d_in[5];
    const float* bq = (const float*)d_in[6];
    const float* wk = (const float*)d_in[7];
    const float* bk = (const float*)d_in[8];
    const float* wv = (const float*)d_in[9];
    const float* bv = (const float*)d_in[10];
    const float* wo = (const float*)d_in[11];
    const float* bo = (const float*)d_in[12];
    const float* w1 = (const float*)d_in[13];
    const float* b1 = (const float*)d_in[14];
    const float* w2 = (const float*)d_in[15];
    const float* b2 = (const float*)d_in[16];

    const size_t MB = 1u << 20;
    char* ws = (char*)d_ws;
    unsigned short* wqkvb = (unsigned short*)(ws + 0 * MB);   // [3072,1024] bf16, 6 MB
    unsigned short* wob  = (unsigned short*)(ws + 6 * MB);
    unsigned short* w1b  = (unsigned short*)(ws + 8 * MB);
    unsigned short* w2b  = (unsigned short*)(ws + 16 * MB);
    unsigned short* hb   = (unsigned short*)(ws + 24 * MB);   // LN1 out, later attn out
    unsigned short* qkvb = (unsigned short*)(ws + 40 * MB);   // Q | K-blocked | V^T-blocked
    unsigned short* qb   = qkvb;
    unsigned short* kblk = qkvb + 8388608;
    unsigned short* vtblk= qkvb + 16777216;
    float*          x1   = (float*)(ws + 56 * MB);            // overlays kblk+vtblk (dead)
    unsigned short* h2b  = (unsigned short*)(ws + 40 * MB);   // overlays qb (dead)
    unsigned short* ff1b = (unsigned short*)(ws + 88 * MB);   // 64 MB
    float*          bqkv = (float*)(ws + 151 * MB);           // [3072] fp32 (inside ff1b, dead then)

    const int D = 1024, FF = 4096, Mrows = 8192;

    cvt_bf16<<<(D * D / 4 + 255) / 256, 256, 0, stream>>>(wq, wqkvb,               D * D / 4);
    cvt_bf16<<<(D * D / 4 + 255) / 256, 256, 0, stream>>>(wk, wqkvb + D * D,       D * D / 4);
    cvt_bf16<<<(D * D / 4 + 255) / 256, 256, 0, stream>>>(wv, wqkvb + 2 * D * D,   D * D / 4);
    cvt_bf16<<<(D * D / 4 + 255) / 256, 256, 0, stream>>>(wo, wob, D * D / 4);
    cvt_bf16<<<(FF * D / 4 + 255) / 256, 256, 0, stream>>>(w1, w1b, FF * D / 4);
    cvt_bf16<<<(FF * D / 4 + 255) / 256, 256, 0, stream>>>(w2, w2b, FF * D / 4);

    hipMemcpyAsync(bqkv,            bq, D * sizeof(float), hipMemcpyDeviceToDevice, stream);
    hipMemcpyAsync(bqkv + D,        bk, D * sizeof(float), hipMemcpyDeviceToDevice, stream);
    hipMemcpyAsync(bqkv + 2 * D,    bv, D * sizeof(float), hipMemcpyDeviceToDevice, stream);

    ln_bf16<<<Mrows, 256, 0, stream>>>(x, ln1_g, ln1_b, hb);

    // fused QKV projection: 256x128 tiles -> 24x32 = 768 wgs
    dim3 gQKV(3 * D / 128, Mrows / 256);
    gemm_nt<6, 256><<<gQKV, 256, 0, stream>>>(hb, wqkvb, bqkv, nullptr, qkvb, D, D);

    attn_kernel<<<1024, 256, 0, stream>>>(qb, kblk, vtblk, hb);

    // WO + resid: keep verified 128x128 (grid 8x64 = 512 wgs)
    dim3 gD(D / 128, Mrows / 128);
    gemm_nt<2, 128><<<gD, 256, 0, stream>>>(hb, wob, bo, x, x1, D, D);

    ln_bf16<<<Mrows, 256, 0, stream>>>(x1, ln2_g, ln2_b, h2b);

    // FF1+gelu: 256x128 tiles -> 32x32 = 1024 wgs
    dim3 gFF(FF / 128, Mrows / 256);
    gemm_nt<1, 256><<<gFF, 256, 0, stream>>>(h2b, w1b, b1, nullptr, ff1b, FF, D);

    // FF2 + resid: keep verified 128x128 (grid 8x64 = 512 wgs)
    gemm_nt<2, 128><<<gD, 256, 0, stream>>>(ff1b, w2b, b2, x1, (float*)d_out, D, FF);
}

// Round 11
// 569.588 us; speedup vs baseline: 1.0566x; 1.0566x over previous
//
#include <hip/hip_runtime.h>
#include <cstdint>
#include <cstddef>

// ---------- types ----------
typedef __attribute__((ext_vector_type(8))) __bf16 bf16x8;
typedef __attribute__((ext_vector_type(4))) float f32x4;
typedef __attribute__((ext_vector_type(8))) unsigned short us8;
typedef __attribute__((ext_vector_type(4))) unsigned short us4;

__device__ inline unsigned short f2bf(float f) {
    unsigned int u = __float_as_uint(f);
    u += 0x7fffu + ((u >> 16) & 1u);   // RNE
    return (unsigned short)(u >> 16);
}

// pack two f32 -> two bf16 by truncation (1 instr); |rel err| < 2^-8, fine for P
__device__ inline unsigned int pkbf_t(float hi, float lo) {
    return __builtin_amdgcn_perm(__float_as_uint(hi), __float_as_uint(lo), 0x07060302u);
}

// raw 2^x: skip the OCML denormal-guard libcall (inputs bounded; subnormal
// results contribute 0 to softmax anyway). 1 instr vs ~6.
__device__ inline float exp2_raw(float x) {
    float r;
    asm("v_exp_f32 %0, %1" : "=v"(r) : "v"(x));
    return r;
}

__device__ inline void async_copy16(const void* g, void* l) {
    __builtin_amdgcn_global_load_lds(
        (const __attribute__((address_space(1))) unsigned int*)g,
        (__attribute__((address_space(3))) unsigned int*)l, 16, 0, 0);
}

// ---------- fused weight prep: 6 cvt kernels + 3 bias memcpys -> 1 launch ----------
// blocks 0..1023 wq->wqkvb | 1024..2047 wk | 2048..3071 wv | 3072..4095 wo->wob |
// 4096..8191 w1->w1b | 8192..12287 w2->w2b | 12288..12290 bias fp32 copies.
// Each block: 256 threads x float4 = 1024 floats.
__global__ __launch_bounds__(256) void prep_weights(
    const float* __restrict__ wq, const float* __restrict__ wk,
    const float* __restrict__ wv, const float* __restrict__ wo,
    const float* __restrict__ w1, const float* __restrict__ w2,
    const float* __restrict__ bq, const float* __restrict__ bk,
    const float* __restrict__ bv,
    unsigned short* __restrict__ wqkvb, unsigned short* __restrict__ wob,
    unsigned short* __restrict__ w1b, unsigned short* __restrict__ w2b,
    float* __restrict__ bqkv) {
    int bid = blockIdx.x;
    if (bid >= 12288) {                       // bias fp32 copy
        int s = bid - 12288;                  // 0,1,2
        const float* bs = (s == 0) ? bq : (s == 1) ? bk : bv;
        ((float4*)(bqkv + s * 1024))[threadIdx.x] = ((const float4*)bs)[threadIdx.x];
        return;
    }
    const float* src;
    unsigned short* dst;
    if (bid < 1024)      { src = wq; dst = wqkvb; }
    else if (bid < 2048) { src = wk; dst = wqkvb + 1048576; bid -= 1024; }
    else if (bid < 3072) { src = wv; dst = wqkvb + 2097152; bid -= 2048; }
    else if (bid < 4096) { src = wo; dst = wob; bid -= 3072; }
    else if (bid < 8192) { src = w1; dst = w1b; bid -= 4096; }
    else                 { src = w2; dst = w2b; bid -= 8192; }
    int i = bid * 256 + threadIdx.x;
    float4 v = ((const float4*)src)[i];
    us4 o;
    o[0] = f2bf(v.x); o[1] = f2bf(v.y); o[2] = f2bf(v.z); o[3] = f2bf(v.w);
    ((us4*)dst)[i] = o;
}

// ---------- layernorm (fp32 in, bf16 out) ----------
__global__ __launch_bounds__(256) void ln_bf16(const float* __restrict__ X,
                                               const float* __restrict__ g,
                                               const float* __restrict__ b,
                                               unsigned short* __restrict__ out) {
    int row = blockIdx.x;
    int t = threadIdx.x;
    float4 v = ((const float4*)(X + (size_t)row * 1024))[t];
    float s  = v.x + v.y + v.z + v.w;
    float s2 = v.x * v.x + v.y * v.y + v.z * v.z + v.w * v.w;
#pragma unroll
    for (int m = 1; m < 64; m <<= 1) {
        s  += __shfl_xor(s, m, 64);
        s2 += __shfl_xor(s2, m, 64);
    }
    __shared__ float red[8];
    int w = t >> 6, l = t & 63;
    if (l == 0) { red[w] = s; red[4 + w] = s2; }
    __syncthreads();
    s  = red[0] + red[1] + red[2] + red[3];
    s2 = red[4] + red[5] + red[6] + red[7];
    float mu  = s * (1.0f / 1024.0f);
    float var = s2 * (1.0f / 1024.0f) - mu * mu;
    float rs  = rsqrtf(var + 1e-5f);
    int c = t * 4;
    float4 gv = *(const float4*)(g + c);
    float4 bv = *(const float4*)(b + c);
    us4 o;
    o[0] = f2bf((v.x - mu) * rs * gv.x + bv.x);
    o[1] = f2bf((v.y - mu) * rs * gv.y + bv.y);
    o[2] = f2bf((v.z - mu) * rs * gv.z + bv.z);
    o[3] = f2bf((v.w - mu) * rs * gv.w + bv.w);
    *(us4*)(out + (size_t)row * 1024 + c) = o;
}

// ---------- NT GEMM (round-9 verified best): 128x128, BK=32, dist-2 + T2 swizzle ----------
// triple-buffered LDS (48 KB, 3 blocks/CU); at iter kt: vmcnt(8) waits tile kt
// (issued 2 iters ago), barrier, stage kt+2 into buf[(kt+2)%3], ds_read buf[kt%3],
// MFMA. One barrier per K-step. XCD-chunked block swizzle.
// T2 swizzle both-sides: rows are 64 B = 4 chunks; f(r)=(r>>1)&3; global source
// chunk pre-XORed, linear LDS dest, read chunk quad^f. Conflicts measured 0 (r9).
// EPI: 1 gelu(bias)->bf16 ; 2 bias+resid->fp32 ; 6 fused QKV epilogue.
#define BM 128
#define BN 128
#define BK 32

template <int EPI>
__global__ __launch_bounds__(256) void gemm_nt(const unsigned short* __restrict__ A,
                                               const unsigned short* __restrict__ B,
                                               const float* __restrict__ bias,
                                               const float* __restrict__ resid,
                                               void* __restrict__ Cout, int N, int K) {
    __shared__ __align__(16) unsigned short As[3][BM * BK];
    __shared__ __align__(16) unsigned short Bs[3][BN * BK];
    const int tid = threadIdx.x;
    const int lane = tid & 63, w = tid >> 6;
    const int quad = lane >> 4, l16 = lane & 15;
    const int wr = w >> 1, wc = w & 1;
    const int swq = quad ^ ((l16 >> 1) & 3);   // swizzled read chunk

    const int gx = gridDim.x;
    const int nwg = gx * gridDim.y;
    int wg = blockIdx.y * gx + blockIdx.x;
    if (!(nwg & 7)) wg = (wg & 7) * (nwg >> 3) + (wg >> 3);
    const size_t bm = (size_t)(wg / gx) * BM;
    const size_t bn = (size_t)(wg % gx) * BN;

#define STAGE(buf, kt)                                                        \
    {                                                                         \
        const int koff = (kt)*BK;                                             \
        _Pragma("unroll") for (int i = 0; i < 2; i++) {                       \
            int e = (i * 256 + tid) * 8;                                      \
            int r = e >> 5;                                                   \
            int csw = (((e >> 3) & 3) ^ ((r >> 1) & 3)) << 3;                 \
            async_copy16(A + (bm + r) * K + koff + csw, &As[buf][e]);         \
            async_copy16(B + (bn + r) * K + koff + csw, &Bs[buf][e]);         \
        }                                                                     \
    }

    f32x4 acc[4][4];
#pragma unroll
    for (int i = 0; i < 4; i++)
#pragma unroll
        for (int j = 0; j < 4; j++) acc[i][j] = (f32x4){0.f, 0.f, 0.f, 0.f};

    const int nk = K / BK;

    STAGE(0, 0);
    STAGE(1, 1);

    for (int kt = 0; kt < nk; ++kt) {
        const int cur = kt % 3;
        if (kt + 1 < nk) {
            asm volatile("s_waitcnt vmcnt(8)" ::: "memory");
        } else {
            asm volatile("s_waitcnt vmcnt(0)" ::: "memory");
        }
        asm volatile("s_barrier" ::: "memory");

        if (kt + 2 < nk) {
            const int nxt2 = (kt + 2) % 3;
            STAGE(nxt2, kt + 2);
        }

        bf16x8 af[4], bfr[4];
#pragma unroll
        for (int mt = 0; mt < 4; mt++)
            af[mt] = *(const bf16x8*)&As[cur][(wr * 64 + mt * 16 + l16) * BK + swq * 8];
#pragma unroll
        for (int nt = 0; nt < 4; nt++)
            bfr[nt] = *(const bf16x8*)&Bs[cur][(wc * 64 + nt * 16 + l16) * BK + swq * 8];

        __builtin_amdgcn_s_setprio(1);
#pragma unroll
        for (int mt = 0; mt < 4; mt++)
#pragma unroll
            for (int nt = 0; nt < 4; nt++)
                acc[mt][nt] = __builtin_amdgcn_mfma_f32_16x16x32_bf16(af[mt], bfr[nt],
                                                                      acc[mt][nt], 0, 0, 0);
        __builtin_amdgcn_s_setprio(0);
        __builtin_amdgcn_sched_barrier(0);
    }
#undef STAGE

#pragma unroll
    for (int mt = 0; mt < 4; mt++) {
#pragma unroll
        for (int nt = 0; nt < 4; nt++) {
#pragma unroll
            for (int r = 0; r < 4; r++) {
                size_t row = bm + wr * 64 + mt * 16 + quad * 4 + r;
                size_t col = bn + wc * 64 + nt * 16 + l16;
                float v = acc[mt][nt][r] + bias[col];
                if (EPI == 1) {
                    v = 0.5f * v * (1.0f + erff(v * 0.70710678118654752f));
                    ((unsigned short*)Cout)[row * N + col] = f2bf(v);
                } else if (EPI == 2) {
                    ((float*)Cout)[row * N + col] = v + resid[row * N + col];
                } else if (EPI == 6) {
                    int sel = (int)(bn >> 10);
                    if (sel == 0) {
                        ((unsigned short*)Cout)[row * 1024 + col] =
                            f2bf(v * 0.18033688011112042f);  // 0.125*log2(e)
                    } else {
                        int key = (int)row & 2047;
                        int bh  = (((int)row >> 11) << 4) | (((int)col >> 6) & 15);
                        int dh  = (int)col & 63;
                        size_t addr;
                        if (sel == 1)
                            addr = 8388608 + (size_t)bh * 131072 +
                                   (size_t)(key >> 6) * 4096 + (size_t)(key & 63) * 64 +
                                   ((((dh >> 3) ^ (key & 7))) << 3) + (dh & 7);
                        else
                            addr = 16777216 + (size_t)bh * 131072 +
                                   (size_t)(key >> 6) * 4096 + (size_t)dh * 64 +
                                   (((((key >> 3) & 7) ^ (dh & 7))) << 3) + (key & 7);
                        ((unsigned short*)Cout)[addr] = f2bf(v);
                    }
                }
            }
        }
    }
}

// ---------- flash attention v6: raw v_exp + l-via-MFMA ----------
// grid 1024: bh = bid & 63 (qblocks of a bh stay on one XCD -> K/V L2-local),
// qblk = bid >> 6. Pipeline = verified v4: dbuf K, late-prefetch V, counted
// vmcnt 4->2->0, raw s_barrier.
// VALU cuts: (1) inline-asm v_exp_f32 (no OCML guard); (2) denominator l
// computed by an extra MFMA with ones-A (D[row][q] = sum_k P[k][q], identical
// across rows/quads) -> removes 24 adds/tile + the cross-quad shfl reduce.
__global__ __launch_bounds__(256) void attn_kernel(const unsigned short* __restrict__ Q,
                                                   const unsigned short* __restrict__ Kb,
                                                   const unsigned short* __restrict__ Vtb,
                                                   unsigned short* __restrict__ O) {
    const int bh   = blockIdx.x & 63;
    const int qblk = blockIdx.x >> 6;
    const int b = bh >> 4, h = bh & 15;
    const int tid = threadIdx.x, lane = tid & 63, w = tid >> 6;
    const int quad = lane >> 4, l16 = lane & 15;
    const int sw = l16 & 7;

    __shared__ __align__(16) unsigned short smem[20480];   // 40 KB
    unsigned short* Vts = smem + 8192;                     // [64 dh][swz 64 key]
    unsigned short* Psw = smem + 12288 + w * 2048;         // per-wave [32 q][swz 64 key]

    const size_t qrow0 = (size_t)b * 2048 + (size_t)qblk * 128 + w * 32;
    const int hcol = h * 64;

    // Q fragment loads first: oldest vmem ops, drained by the first vmcnt(4)
    bf16x8 qfr[2][2];
#pragma unroll
    for (int qf = 0; qf < 2; qf++)
#pragma unroll
        for (int kp = 0; kp < 2; kp++)
            qfr[qf][kp] = *(const bf16x8*)(Q + (qrow0 + qf * 16 + l16) * 1024 +
                                           hcol + kp * 32 + quad * 8);

    const unsigned short* ksrc = Kb  + (size_t)bh * 131072;
    const unsigned short* vsrc = Vtb + (size_t)bh * 131072;

    // prologue: stage K(0) -> buf0, V(0) -> Vts
    async_copy16(ksrc + tid * 8,        smem + tid * 8);
    async_copy16(ksrc + 2048 + tid * 8, smem + 2048 + tid * 8);
    async_copy16(vsrc + tid * 8,        Vts + tid * 8);
    async_copy16(vsrc + 2048 + tid * 8, Vts + 2048 + tid * 8);

    // ones A-fragment for the denominator MFMA
    us8 one_us;
#pragma unroll
    for (int j = 0; j < 8; j++) one_us[j] = 0x3F80;        // bf16 1.0
    const bf16x8 ones = *(const bf16x8*)&one_us;

    f32x4 acc[4][2];
#pragma unroll
    for (int df = 0; df < 4; df++)
#pragma unroll
        for (int qf = 0; qf < 2; qf++) acc[df][qf] = (f32x4){0.f, 0.f, 0.f, 0.f};
    f32x4 acc_l[2] = {(f32x4){0.f, 0.f, 0.f, 0.f}, (f32x4){0.f, 0.f, 0.f, 0.f}};

    for (int kt = 0; kt < 32; ++kt) {
        unsigned short* Ks = (kt & 1) ? (smem + 4096) : smem;   // current K buffer
        if (kt < 31) {
            unsigned short* Kd = (kt & 1) ? smem : (smem + 4096);
            const unsigned short* kg = ksrc + (size_t)(kt + 1) * 4096;
            async_copy16(kg + tid * 8,        Kd + tid * 8);
            async_copy16(kg + 2048 + tid * 8, Kd + 2048 + tid * 8);
            asm volatile("s_waitcnt vmcnt(4)" ::: "memory");    // K(kt) landed
        } else {
            asm volatile("s_waitcnt vmcnt(2)" ::: "memory");    // K(31) landed
        }
        asm volatile("s_barrier" ::: "memory");

        // S^T[64 key][32 q] = K Q^T
        f32x4 s[4][2];
#pragma unroll
        for (int mf = 0; mf < 4; mf++)
#pragma unroll
            for (int qf = 0; qf < 2; qf++) s[mf][qf] = (f32x4){0.f, 0.f, 0.f, 0.f};
        __builtin_amdgcn_s_setprio(1);
#pragma unroll
        for (int kp = 0; kp < 2; kp++) {
#pragma unroll
            for (int mf = 0; mf < 4; mf++) {
                bf16x8 kf = *(const bf16x8*)&Ks[(mf * 16 + l16) * 64 +
                                                (((kp * 4 + quad) ^ sw) << 3)];
#pragma unroll
                for (int qf = 0; qf < 2; qf++)
                    s[mf][qf] = __builtin_amdgcn_mfma_f32_16x16x32_bf16(kf, qfr[qf][kp],
                                                                        s[mf][qf], 0, 0, 0);
            }
        }
        __builtin_amdgcn_s_setprio(0);

        // p = exp2(s) (raw v_exp); trunc-pack into Psw (no VALU row-sum)
#pragma unroll
        for (int mf = 0; mf < 4; mf++)
#pragma unroll
            for (int qf = 0; qf < 2; qf++) {
                float e0 = exp2_raw(s[mf][qf][0]);
                float e1 = exp2_raw(s[mf][qf][1]);
                float e2 = exp2_raw(s[mf][qf][2]);
                float e3 = exp2_raw(s[mf][qf][3]);
                *(uint2*)&Psw[(qf * 16 + l16) * 64 +
                              (((mf * 2 + (quad >> 1)) ^ sw) << 3) + ((quad & 1) << 2)] =
                    make_uint2(pkbf_t(e1, e0), pkbf_t(e3, e2));
            }
        asm volatile("s_waitcnt lgkmcnt(0)" ::: "memory");

        if (kt < 31) {
            asm volatile("s_waitcnt vmcnt(2)" ::: "memory");    // V(kt) landed
        } else {
            asm volatile("s_waitcnt vmcnt(0)" ::: "memory");
        }
        asm volatile("s_barrier" ::: "memory");

        // out^T[64 dh][32 q] += V^T P^T ; denominator row via ones-MFMA
        __builtin_amdgcn_s_setprio(1);
#pragma unroll
        for (int kp = 0; kp < 2; kp++) {
            bf16x8 pf[2];
#pragma unroll
            for (int qf = 0; qf < 2; qf++) {
                pf[qf] = *(const bf16x8*)&Psw[(qf * 16 + l16) * 64 +
                                              (((kp * 4 + quad) ^ sw) << 3)];
                acc_l[qf] = __builtin_amdgcn_mfma_f32_16x16x32_bf16(ones, pf[qf],
                                                                    acc_l[qf], 0, 0, 0);
            }
#pragma unroll
            for (int df = 0; df < 4; df++) {
                bf16x8 vf = *(const bf16x8*)&Vts[(df * 16 + l16) * 64 +
                                                 (((kp * 4 + quad) ^ sw) << 3)];
#pragma unroll
                for (int qf = 0; qf < 2; qf++)
                    acc[df][qf] = __builtin_amdgcn_mfma_f32_16x16x32_bf16(vf, pf[qf],
                                                                          acc[df][qf], 0, 0, 0);
            }
        }
        __builtin_amdgcn_s_setprio(0);

        asm volatile("s_barrier" ::: "memory");
        if (kt < 31) {
            const unsigned short* vg = vsrc + (size_t)(kt + 1) * 4096;
            async_copy16(vg + tid * 8,        Vts + tid * 8);
            async_copy16(vg + 2048 + tid * 8, Vts + 2048 + tid * 8);
        }
    }

    // epilogue: normalize, transpose through LDS, coalesced bf16 store.
    // acc_l rows are all identical (ones-A) -> inv uniform across quads.
    __syncthreads();
    float inv[2] = {1.f / acc_l[0][0], 1.f / acc_l[1][0]};
    unsigned short* Ls = smem;   // [64 dh][128 q] stride 130
#pragma unroll
    for (int df = 0; df < 4; df++)
#pragma unroll
        for (int qf = 0; qf < 2; qf++)
#pragma unroll
            for (int r = 0; r < 4; r++) {
                int dh = df * 16 + quad * 4 + r;
                int q  = w * 32 + qf * 16 + l16;
                Ls[dh * 130 + q] =
                    (unsigned short)((__float_as_uint(acc[df][qf][r] * inv[qf]) + 0x8000u) >> 16);
            }
    __syncthreads();
    int q = tid >> 1, dh0 = (tid & 1) * 32;
    size_t obase = ((size_t)b * 2048 + (size_t)qblk * 128 + q) * 1024 + hcol + dh0;
#pragma unroll
    for (int c = 0; c < 4; c++) {
        us8 o;
#pragma unroll
        for (int j = 0; j < 8; j++) o[j] = Ls[(dh0 + c * 8 + j) * 130 + q];
        *(us8*)(O + obase + c * 8) = o;
    }
}

// ---------- launch ----------
extern "C" void kernel_launch(void* const* d_in, const int* in_sizes, int n_in,
                              void* d_out, int out_size, void* d_ws, size_t ws_size,
                              hipStream_t stream) {
    const float* x     = (const float*)d_in[0];
    const float* ln1_g = (const float*)d_in[1];
    const float* ln1_b = (const float*)d_in[2];
    const float* ln2_g = (const float*)d_in[3];
    const float* ln2_b = (const float*)d_in[4];
    const float* wq = (const float*)d_in[5];
    const float* bq = (const float*)d_in[6];
    const float* wk = (const float*)d_in[7];
    const float* bk = (const float*)d_in[8];
    const float* wv = (const float*)d_in[9];
    const float* bv = (const float*)d_in[10];
    const float* wo = (const float*)d_in[11];
    const float* bo = (const float*)d_in[12];
    const float* w1 = (const float*)d_in[13];
    const float* b1 = (const float*)d_in[14];
    const float* w2 = (const float*)d_in[15];
    const float* b2 = (const float*)d_in[16];

    const size_t MB = 1u << 20;
    char* ws = (char*)d_ws;
    unsigned short* wqkvb = (unsigned short*)(ws + 0 * MB);   // [3072,1024] bf16, 6 MB
    unsigned short* wob  = (unsigned short*)(ws + 6 * MB);
    unsigned short* w1b  = (unsigned short*)(ws + 8 * MB);
    unsigned short* w2b  = (unsigned short*)(ws + 16 * MB);
    unsigned short* hb   = (unsigned short*)(ws + 24 * MB);   // LN1 out, later attn out
    unsigned short* qkvb = (unsigned short*)(ws + 40 * MB);   // Q | K-blocked | V^T-blocked
    unsigned short* qb   = qkvb;
    unsigned short* kblk = qkvb + 8388608;
    unsigned short* vtblk= qkvb + 16777216;
    float*          x1   = (float*)(ws + 56 * MB);            // overlays kblk+vtblk (dead)
    unsigned short* h2b  = (unsigned short*)(ws + 40 * MB);   // overlays qb (dead)
    unsigned short* ff1b = (unsigned short*)(ws + 88 * MB);   // 64 MB
    float*          bqkv = (float*)(ws + 151 * MB);           // [3072] fp32 (inside ff1b, dead then)

    const int D = 1024, FF = 4096, Mrows = 8192;

    // one launch replaces 6 cvt kernels + 3 bias memcpys
    prep_weights<<<12291, 256, 0, stream>>>(wq, wk, wv, wo, w1, w2, bq, bk, bv,
                                            wqkvb, wob, w1b, w2b, bqkv);

    ln_bf16<<<Mrows, 256, 0, stream>>>(x, ln1_g, ln1_b, hb);

    // fused QKV projection
    dim3 gQKV(3 * D / BN, Mrows / BM);
    gemm_nt<6><<<gQKV, 256, 0, stream>>>(hb, wqkvb, bqkv, nullptr, qkvb, D, D);

    attn_kernel<<<1024, 256, 0, stream>>>(qb, kblk, vtblk, hb);

    dim3 gD(D / BN, Mrows / BM);
    gemm_nt<2><<<gD, 256, 0, stream>>>(hb, wob, bo, x, x1, D, D);           // O + resid

    ln_bf16<<<Mrows, 256, 0, stream>>>(x1, ln2_g, ln2_b, h2b);

    dim3 gFF(FF / BN, Mrows / BM);
    gemm_nt<1><<<gFF, 256, 0, stream>>>(h2b, w1b, b1, nullptr, ff1b, FF, D);  // FF1+gelu

    gemm_nt<2><<<gD, 256, 0, stream>>>(ff1b, w2b, b2, x1, (float*)d_out, D, FF);  // FF2
}

// Round 12
// 553.832 us; speedup vs baseline: 1.0867x; 1.0284x over previous
//
#include <hip/hip_runtime.h>
#include <cstdint>
#include <cstddef>

// ---------- types ----------
typedef __attribute__((ext_vector_type(8))) __bf16 bf16x8;
typedef __attribute__((ext_vector_type(4))) float f32x4;
typedef __attribute__((ext_vector_type(8))) unsigned short us8;
typedef __attribute__((ext_vector_type(4))) unsigned short us4;

__device__ inline unsigned short f2bf(float f) {
    unsigned int u = __float_as_uint(f);
    u += 0x7fffu + ((u >> 16) & 1u);   // RNE
    return (unsigned short)(u >> 16);
}

// pack two f32 -> two bf16 by truncation (1 instr); |rel err| < 2^-8, fine for P
__device__ inline unsigned int pkbf_t(float hi, float lo) {
    return __builtin_amdgcn_perm(__float_as_uint(hi), __float_as_uint(lo), 0x07060302u);
}

// raw 2^x: skip the OCML denormal-guard libcall (inputs bounded; subnormal
// results contribute 0 downstream). 1 instr vs ~6.
__device__ inline float exp2_raw(float x) {
    float r;
    asm("v_exp_f32 %0, %1" : "=v"(r) : "v"(x));
    return r;
}

__device__ inline float rcp_raw(float x) {
    float r;
    asm("v_rcp_f32 %0, %1" : "=v"(r) : "v"(x));
    return r;
}

// erf via Abramowitz-Stegun 7.1.26 (max abs err 1.5e-7 -- below bf16 output
// quantization, i.e. numerically identical to the erff libcall here) using
// raw v_rcp + v_exp. ~14 VALU + 2 trans vs the ~30-instr OCML erff libcall.
__device__ inline float erf_fast(float x) {
    float ax = fabsf(x);
    float t  = rcp_raw(1.0f + 0.3275911f * ax);
    float y  = t * (0.254829592f +
               t * (-0.284496736f +
               t * (1.421413741f +
               t * (-1.453152027f +
               t * 1.061405429f))));
    float e  = exp2_raw(-1.44269504088896f * ax * ax);   // e^(-x^2)
    float r  = 1.0f - y * e;
    // copysign(r, x)
    return __uint_as_float((__float_as_uint(r) & 0x7fffffffu) |
                           (__float_as_uint(x) & 0x80000000u));
}

__device__ inline void async_copy16(const void* g, void* l) {
    __builtin_amdgcn_global_load_lds(
        (const __attribute__((address_space(1))) unsigned int*)g,
        (__attribute__((address_space(3))) unsigned int*)l, 16, 0, 0);
}

// ---------- fused weight prep: 6 cvt kernels + 3 bias memcpys -> 1 launch ----------
// blocks 0..1023 wq->wqkvb | 1024..2047 wk | 2048..3071 wv | 3072..4095 wo->wob |
// 4096..8191 w1->w1b | 8192..12287 w2->w2b | 12288..12290 bias fp32 copies.
// Each block: 256 threads x float4 = 1024 floats.
__global__ __launch_bounds__(256) void prep_weights(
    const float* __restrict__ wq, const float* __restrict__ wk,
    const float* __restrict__ wv, const float* __restrict__ wo,
    const float* __restrict__ w1, const float* __restrict__ w2,
    const float* __restrict__ bq, const float* __restrict__ bk,
    const float* __restrict__ bv,
    unsigned short* __restrict__ wqkvb, unsigned short* __restrict__ wob,
    unsigned short* __restrict__ w1b, unsigned short* __restrict__ w2b,
    float* __restrict__ bqkv) {
    int bid = blockIdx.x;
    if (bid >= 12288) {                       // bias fp32 copy
        int s = bid - 12288;                  // 0,1,2
        const float* bs = (s == 0) ? bq : (s == 1) ? bk : bv;
        ((float4*)(bqkv + s * 1024))[threadIdx.x] = ((const float4*)bs)[threadIdx.x];
        return;
    }
    const float* src;
    unsigned short* dst;
    if (bid < 1024)      { src = wq; dst = wqkvb; }
    else if (bid < 2048) { src = wk; dst = wqkvb + 1048576; bid -= 1024; }
    else if (bid < 3072) { src = wv; dst = wqkvb + 2097152; bid -= 2048; }
    else if (bid < 4096) { src = wo; dst = wob; bid -= 3072; }
    else if (bid < 8192) { src = w1; dst = w1b; bid -= 4096; }
    else                 { src = w2; dst = w2b; bid -= 8192; }
    int i = bid * 256 + threadIdx.x;
    float4 v = ((const float4*)src)[i];
    us4 o;
    o[0] = f2bf(v.x); o[1] = f2bf(v.y); o[2] = f2bf(v.z); o[3] = f2bf(v.w);
    ((us4*)dst)[i] = o;
}

// ---------- layernorm (fp32 in, bf16 out) ----------
__global__ __launch_bounds__(256) void ln_bf16(const float* __restrict__ X,
                                               const float* __restrict__ g,
                                               const float* __restrict__ b,
                                               unsigned short* __restrict__ out) {
    int row = blockIdx.x;
    int t = threadIdx.x;
    float4 v = ((const float4*)(X + (size_t)row * 1024))[t];
    float s  = v.x + v.y + v.z + v.w;
    float s2 = v.x * v.x + v.y * v.y + v.z * v.z + v.w * v.w;
#pragma unroll
    for (int m = 1; m < 64; m <<= 1) {
        s  += __shfl_xor(s, m, 64);
        s2 += __shfl_xor(s2, m, 64);
    }
    __shared__ float red[8];
    int w = t >> 6, l = t & 63;
    if (l == 0) { red[w] = s; red[4 + w] = s2; }
    __syncthreads();
    s  = red[0] + red[1] + red[2] + red[3];
    s2 = red[4] + red[5] + red[6] + red[7];
    float mu  = s * (1.0f / 1024.0f);
    float var = s2 * (1.0f / 1024.0f) - mu * mu;
    float rs  = rsqrtf(var + 1e-5f);
    int c = t * 4;
    float4 gv = *(const float4*)(g + c);
    float4 bv = *(const float4*)(b + c);
    us4 o;
    o[0] = f2bf((v.x - mu) * rs * gv.x + bv.x);
    o[1] = f2bf((v.y - mu) * rs * gv.y + bv.y);
    o[2] = f2bf((v.z - mu) * rs * gv.z + bv.z);
    o[3] = f2bf((v.w - mu) * rs * gv.w + bv.w);
    *(us4*)(out + (size_t)row * 1024 + c) = o;
}

// ---------- NT GEMM (r9/r11 verified best): 128x128, BK=32, dist-2 + T2 swizzle ----------
// triple-buffered LDS (48 KB, 3 blocks/CU); at iter kt: vmcnt(8) waits tile kt
// (issued 2 iters ago), barrier, stage kt+2 into buf[(kt+2)%3], ds_read buf[kt%3],
// MFMA. One barrier per K-step. XCD-chunked block swizzle.
// T2 swizzle both-sides: rows are 64 B = 4 chunks; f(r)=(r>>1)&3; global source
// chunk pre-XORed, linear LDS dest, read chunk quad^f. Conflicts measured 0 (r9).
// EPI: 1 gelu(bias)->bf16 (erf_fast) ; 2 bias+resid->fp32 ; 6 fused QKV epilogue.
#define BM 128
#define BN 128
#define BK 32

template <int EPI>
__global__ __launch_bounds__(256) void gemm_nt(const unsigned short* __restrict__ A,
                                               const unsigned short* __restrict__ B,
                                               const float* __restrict__ bias,
                                               const float* __restrict__ resid,
                                               void* __restrict__ Cout, int N, int K) {
    __shared__ __align__(16) unsigned short As[3][BM * BK];
    __shared__ __align__(16) unsigned short Bs[3][BN * BK];
    const int tid = threadIdx.x;
    const int lane = tid & 63, w = tid >> 6;
    const int quad = lane >> 4, l16 = lane & 15;
    const int wr = w >> 1, wc = w & 1;
    const int swq = quad ^ ((l16 >> 1) & 3);   // swizzled read chunk

    const int gx = gridDim.x;
    const int nwg = gx * gridDim.y;
    int wg = blockIdx.y * gx + blockIdx.x;
    if (!(nwg & 7)) wg = (wg & 7) * (nwg >> 3) + (wg >> 3);
    const size_t bm = (size_t)(wg / gx) * BM;
    const size_t bn = (size_t)(wg % gx) * BN;

#define STAGE(buf, kt)                                                        \
    {                                                                         \
        const int koff = (kt)*BK;                                             \
        _Pragma("unroll") for (int i = 0; i < 2; i++) {                       \
            int e = (i * 256 + tid) * 8;                                      \
            int r = e >> 5;                                                   \
            int csw = (((e >> 3) & 3) ^ ((r >> 1) & 3)) << 3;                 \
            async_copy16(A + (bm + r) * K + koff + csw, &As[buf][e]);         \
            async_copy16(B + (bn + r) * K + koff + csw, &Bs[buf][e]);         \
        }                                                                     \
    }

    f32x4 acc[4][4];
#pragma unroll
    for (int i = 0; i < 4; i++)
#pragma unroll
        for (int j = 0; j < 4; j++) acc[i][j] = (f32x4){0.f, 0.f, 0.f, 0.f};

    const int nk = K / BK;

    STAGE(0, 0);
    STAGE(1, 1);

    for (int kt = 0; kt < nk; ++kt) {
        const int cur = kt % 3;
        if (kt + 1 < nk) {
            asm volatile("s_waitcnt vmcnt(8)" ::: "memory");
        } else {
            asm volatile("s_waitcnt vmcnt(0)" ::: "memory");
        }
        asm volatile("s_barrier" ::: "memory");

        if (kt + 2 < nk) {
            const int nxt2 = (kt + 2) % 3;
            STAGE(nxt2, kt + 2);
        }

        bf16x8 af[4], bfr[4];
#pragma unroll
        for (int mt = 0; mt < 4; mt++)
            af[mt] = *(const bf16x8*)&As[cur][(wr * 64 + mt * 16 + l16) * BK + swq * 8];
#pragma unroll
        for (int nt = 0; nt < 4; nt++)
            bfr[nt] = *(const bf16x8*)&Bs[cur][(wc * 64 + nt * 16 + l16) * BK + swq * 8];

        __builtin_amdgcn_s_setprio(1);
#pragma unroll
        for (int mt = 0; mt < 4; mt++)
#pragma unroll
            for (int nt = 0; nt < 4; nt++)
                acc[mt][nt] = __builtin_amdgcn_mfma_f32_16x16x32_bf16(af[mt], bfr[nt],
                                                                      acc[mt][nt], 0, 0, 0);
        __builtin_amdgcn_s_setprio(0);
        __builtin_amdgcn_sched_barrier(0);
    }
#undef STAGE

#pragma unroll
    for (int mt = 0; mt < 4; mt++) {
#pragma unroll
        for (int nt = 0; nt < 4; nt++) {
#pragma unroll
            for (int r = 0; r < 4; r++) {
                size_t row = bm + wr * 64 + mt * 16 + quad * 4 + r;
                size_t col = bn + wc * 64 + nt * 16 + l16;
                float v = acc[mt][nt][r] + bias[col];
                if (EPI == 1) {
                    v = 0.5f * v * (1.0f + erf_fast(v * 0.70710678118654752f));
                    ((unsigned short*)Cout)[row * N + col] = f2bf(v);
                } else if (EPI == 2) {
                    ((float*)Cout)[row * N + col] = v + resid[row * N + col];
                } else if (EPI == 6) {
                    int sel = (int)(bn >> 10);
                    if (sel == 0) {
                        ((unsigned short*)Cout)[row * 1024 + col] =
                            f2bf(v * 0.18033688011112042f);  // 0.125*log2(e)
                    } else {
                        int key = (int)row & 2047;
                        int bh  = (((int)row >> 11) << 4) | (((int)col >> 6) & 15);
                        int dh  = (int)col & 63;
                        size_t addr;
                        if (sel == 1)
                            addr = 8388608 + (size_t)bh * 131072 +
                                   (size_t)(key >> 6) * 4096 + (size_t)(key & 63) * 64 +
                                   ((((dh >> 3) ^ (key & 7))) << 3) + (dh & 7);
                        else
                            addr = 16777216 + (size_t)bh * 131072 +
                                   (size_t)(key >> 6) * 4096 + (size_t)dh * 64 +
                                   (((((key >> 3) & 7) ^ (dh & 7))) << 3) + (key & 7);
                        ((unsigned short*)Cout)[addr] = f2bf(v);
                    }
                }
            }
        }
    }
}

// ---------- flash attention v6: raw v_exp + l-via-MFMA ----------
// grid 1024: bh = bid & 63 (qblocks of a bh stay on one XCD -> K/V L2-local),
// qblk = bid >> 6. Pipeline = verified v4: dbuf K, late-prefetch V, counted
// vmcnt 4->2->0, raw s_barrier.
// VALU cuts: (1) inline-asm v_exp_f32 (no OCML guard); (2) denominator l
// computed by an extra MFMA with ones-A (D[row][q] = sum_k P[k][q], identical
// across rows/quads) -> removes 24 adds/tile + the cross-quad shfl reduce.
__global__ __launch_bounds__(256) void attn_kernel(const unsigned short* __restrict__ Q,
                                                   const unsigned short* __restrict__ Kb,
                                                   const unsigned short* __restrict__ Vtb,
                                                   unsigned short* __restrict__ O) {
    const int bh   = blockIdx.x & 63;
    const int qblk = blockIdx.x >> 6;
    const int b = bh >> 4, h = bh & 15;
    const int tid = threadIdx.x, lane = tid & 63, w = tid >> 6;
    const int quad = lane >> 4, l16 = lane & 15;
    const int sw = l16 & 7;

    __shared__ __align__(16) unsigned short smem[20480];   // 40 KB
    unsigned short* Vts = smem + 8192;                     // [64 dh][swz 64 key]
    unsigned short* Psw = smem + 12288 + w * 2048;         // per-wave [32 q][swz 64 key]

    const size_t qrow0 = (size_t)b * 2048 + (size_t)qblk * 128 + w * 32;
    const int hcol = h * 64;

    // Q fragment loads first: oldest vmem ops, drained by the first vmcnt(4)
    bf16x8 qfr[2][2];
#pragma unroll
    for (int qf = 0; qf < 2; qf++)
#pragma unroll
        for (int kp = 0; kp < 2; kp++)
            qfr[qf][kp] = *(const bf16x8*)(Q + (qrow0 + qf * 16 + l16) * 1024 +
                                           hcol + kp * 32 + quad * 8);

    const unsigned short* ksrc = Kb  + (size_t)bh * 131072;
    const unsigned short* vsrc = Vtb + (size_t)bh * 131072;

    // prologue: stage K(0) -> buf0, V(0) -> Vts
    async_copy16(ksrc + tid * 8,        smem + tid * 8);
    async_copy16(ksrc + 2048 + tid * 8, smem + 2048 + tid * 8);
    async_copy16(vsrc + tid * 8,        Vts + tid * 8);
    async_copy16(vsrc + 2048 + tid * 8, Vts + 2048 + tid * 8);

    // ones A-fragment for the denominator MFMA
    us8 one_us;
#pragma unroll
    for (int j = 0; j < 8; j++) one_us[j] = 0x3F80;        // bf16 1.0
    const bf16x8 ones = *(const bf16x8*)&one_us;

    f32x4 acc[4][2];
#pragma unroll
    for (int df = 0; df < 4; df++)
#pragma unroll
        for (int qf = 0; qf < 2; qf++) acc[df][qf] = (f32x4){0.f, 0.f, 0.f, 0.f};
    f32x4 acc_l[2] = {(f32x4){0.f, 0.f, 0.f, 0.f}, (f32x4){0.f, 0.f, 0.f, 0.f}};

    for (int kt = 0; kt < 32; ++kt) {
        unsigned short* Ks = (kt & 1) ? (smem + 4096) : smem;   // current K buffer
        if (kt < 31) {
            unsigned short* Kd = (kt & 1) ? smem : (smem + 4096);
            const unsigned short* kg = ksrc + (size_t)(kt + 1) * 4096;
            async_copy16(kg + tid * 8,        Kd + tid * 8);
            async_copy16(kg + 2048 + tid * 8, Kd + 2048 + tid * 8);
            asm volatile("s_waitcnt vmcnt(4)" ::: "memory");    // K(kt) landed
        } else {
            asm volatile("s_waitcnt vmcnt(2)" ::: "memory");    // K(31) landed
        }
        asm volatile("s_barrier" ::: "memory");

        // S^T[64 key][32 q] = K Q^T
        f32x4 s[4][2];
#pragma unroll
        for (int mf = 0; mf < 4; mf++)
#pragma unroll
            for (int qf = 0; qf < 2; qf++) s[mf][qf] = (f32x4){0.f, 0.f, 0.f, 0.f};
        __builtin_amdgcn_s_setprio(1);
#pragma unroll
        for (int kp = 0; kp < 2; kp++) {
#pragma unroll
            for (int mf = 0; mf < 4; mf++) {
                bf16x8 kf = *(const bf16x8*)&Ks[(mf * 16 + l16) * 64 +
                                                (((kp * 4 + quad) ^ sw) << 3)];
#pragma unroll
                for (int qf = 0; qf < 2; qf++)
                    s[mf][qf] = __builtin_amdgcn_mfma_f32_16x16x32_bf16(kf, qfr[qf][kp],
                                                                        s[mf][qf], 0, 0, 0);
            }
        }
        __builtin_amdgcn_s_setprio(0);

        // p = exp2(s) (raw v_exp); trunc-pack into Psw (no VALU row-sum)
#pragma unroll
        for (int mf = 0; mf < 4; mf++)
#pragma unroll
            for (int qf = 0; qf < 2; qf++) {
                float e0 = exp2_raw(s[mf][qf][0]);
                float e1 = exp2_raw(s[mf][qf][1]);
                float e2 = exp2_raw(s[mf][qf][2]);
                float e3 = exp2_raw(s[mf][qf][3]);
                *(uint2*)&Psw[(qf * 16 + l16) * 64 +
                              (((mf * 2 + (quad >> 1)) ^ sw) << 3) + ((quad & 1) << 2)] =
                    make_uint2(pkbf_t(e1, e0), pkbf_t(e3, e2));
            }
        asm volatile("s_waitcnt lgkmcnt(0)" ::: "memory");

        if (kt < 31) {
            asm volatile("s_waitcnt vmcnt(2)" ::: "memory");    // V(kt) landed
        } else {
            asm volatile("s_waitcnt vmcnt(0)" ::: "memory");
        }
        asm volatile("s_barrier" ::: "memory");

        // out^T[64 dh][32 q] += V^T P^T ; denominator row via ones-MFMA
        __builtin_amdgcn_s_setprio(1);
#pragma unroll
        for (int kp = 0; kp < 2; kp++) {
            bf16x8 pf[2];
#pragma unroll
            for (int qf = 0; qf < 2; qf++) {
                pf[qf] = *(const bf16x8*)&Psw[(qf * 16 + l16) * 64 +
                                              (((kp * 4 + quad) ^ sw) << 3)];
                acc_l[qf] = __builtin_amdgcn_mfma_f32_16x16x32_bf16(ones, pf[qf],
                                                                    acc_l[qf], 0, 0, 0);
            }
#pragma unroll
            for (int df = 0; df < 4; df++) {
                bf16x8 vf = *(const bf16x8*)&Vts[(df * 16 + l16) * 64 +
                                                 (((kp * 4 + quad) ^ sw) << 3)];
#pragma unroll
                for (int qf = 0; qf < 2; qf++)
                    acc[df][qf] = __builtin_amdgcn_mfma_f32_16x16x32_bf16(vf, pf[qf],
                                                                          acc[df][qf], 0, 0, 0);
            }
        }
        __builtin_amdgcn_s_setprio(0);

        asm volatile("s_barrier" ::: "memory");
        if (kt < 31) {
            const unsigned short* vg = vsrc + (size_t)(kt + 1) * 4096;
            async_copy16(vg + tid * 8,        Vts + tid * 8);
            async_copy16(vg + 2048 + tid * 8, Vts + 2048 + tid * 8);
        }
    }

    // epilogue: normalize, transpose through LDS, coalesced bf16 store.
    // acc_l rows are all identical (ones-A) -> inv uniform across quads.
    __syncthreads();
    float inv[2] = {1.f / acc_l[0][0], 1.f / acc_l[1][0]};
    unsigned short* Ls = smem;   // [64 dh][128 q] stride 130
#pragma unroll
    for (int df = 0; df < 4; df++)
#pragma unroll
        for (int qf = 0; qf < 2; qf++)
#pragma unroll
            for (int r = 0; r < 4; r++) {
                int dh = df * 16 + quad * 4 + r;
                int q  = w * 32 + qf * 16 + l16;
                Ls[dh * 130 + q] =
                    (unsigned short)((__float_as_uint(acc[df][qf][r] * inv[qf]) + 0x8000u) >> 16);
            }
    __syncthreads();
    int q = tid >> 1, dh0 = (tid & 1) * 32;
    size_t obase = ((size_t)b * 2048 + (size_t)qblk * 128 + q) * 1024 + hcol + dh0;
#pragma unroll
    for (int c = 0; c < 4; c++) {
        us8 o;
#pragma unroll
        for (int j = 0; j < 8; j++) o[j] = Ls[(dh0 + c * 8 + j) * 130 + q];
        *(us8*)(O + obase + c * 8) = o;
    }
}

// ---------- launch ----------
extern "C" void kernel_launch(void* const* d_in, const int* in_sizes, int n_in,
                              void* d_out, int out_size, void* d_ws, size_t ws_size,
                              hipStream_t stream) {
    const float* x     = (const float*)d_in[0];
    const float* ln1_g = (const float*)d_in[1];
    const float* ln1_b = (const float*)d_in[2];
    const float* ln2_g = (const float*)d_in[3];
    const float* ln2_b = (const float*)d_in[4];
    const float* wq = (const float*)d_in[5];
    const float* bq = (const float*)d_in[6];
    const float* wk = (const float*)d_in[7];
    const float* bk = (const float*)d_in[8];
    const float* wv = (const float*)d_in[9];
    const float* bv = (const float*)d_in[10];
    const float* wo = (const float*)d_in[11];
    const float* bo = (const float*)d_in[12];
    const float* w1 = (const float*)d_in[13];
    const float* b1 = (const float*)d_in[14];
    const float* w2 = (const float*)d_in[15];
    const float* b2 = (const float*)d_in[16];

    const size_t MB = 1u << 20;
    char* ws = (char*)d_ws;
    unsigned short* wqkvb = (unsigned short*)(ws + 0 * MB);   // [3072,1024] bf16, 6 MB
    unsigned short* wob  = (unsigned short*)(ws + 6 * MB);
    unsigned short* w1b  = (unsigned short*)(ws + 8 * MB);
    unsigned short* w2b  = (unsigned short*)(ws + 16 * MB);
    unsigned short* hb   = (unsigned short*)(ws + 24 * MB);   // LN1 out, later attn out
    unsigned short* qkvb = (unsigned short*)(ws + 40 * MB);   // Q | K-blocked | V^T-blocked
    unsigned short* qb   = qkvb;
    unsigned short* kblk = qkvb + 8388608;
    unsigned short* vtblk= qkvb + 16777216;
    float*          x1   = (float*)(ws + 56 * MB);            // overlays kblk+vtblk (dead)
    unsigned short* h2b  = (unsigned short*)(ws + 40 * MB);   // overlays qb (dead)
    unsigned short* ff1b = (unsigned short*)(ws + 88 * MB);   // 64 MB
    float*          bqkv = (float*)(ws + 151 * MB);           // [3072] fp32 (inside ff1b, dead then)

    const int D = 1024, FF = 4096, Mrows = 8192;

    // one launch replaces 6 cvt kernels + 3 bias memcpys
    prep_weights<<<12291, 256, 0, stream>>>(wq, wk, wv, wo, w1, w2, bq, bk, bv,
                                            wqkvb, wob, w1b, w2b, bqkv);

    ln_bf16<<<Mrows, 256, 0, stream>>>(x, ln1_g, ln1_b, hb);

    // fused QKV projection
    dim3 gQKV(3 * D / BN, Mrows / BM);
    gemm_nt<6><<<gQKV, 256, 0, stream>>>(hb, wqkvb, bqkv, nullptr, qkvb, D, D);

    attn_kernel<<<1024, 256, 0, stream>>>(qb, kblk, vtblk, hb);

    dim3 gD(D / BN, Mrows / BM);
    gemm_nt<2><<<gD, 256, 0, stream>>>(hb, wob, bo, x, x1, D, D);           // O + resid

    ln_bf16<<<Mrows, 256, 0, stream>>>(x1, ln2_g, ln2_b, h2b);

    dim3 gFF(FF / BN, Mrows / BM);
    gemm_nt<1><<<gFF, 256, 0, stream>>>(h2b, w1b, b1, nullptr, ff1b, FF, D);  // FF1+gelu

    gemm_nt<2><<<gD, 256, 0, stream>>>(ff1b, w2b, b2, x1, (float*)d_out, D, FF);  // FF2
}